// Round 1
// baseline (1051.874 us; speedup 1.0000x reference)
//
#include <hip/hip_runtime.h>

#define EPSF 1e-5f

// ---------------- workspace layout (float element offsets) ----------------
// P0: conv ping buffer  [128*24*40*40]
// P1: conv pong buffer  [128*24*20*20]
#define OFF_P0   0
#define OFF_P1   4915200
#define OFF_SS   6144000   // 4 layers * (2 imgs * (24 scale + 24 shift)) = 4*96
#define OFF_FEAT 6144384   // 128*25*26
#define OFF_U    6227584   // 64*25*256
#define OFF_V    6637184   // 64*25*256
#define OFF_Q    7046784   // 64*256
#define OFF_WT   7063168   // 3*256*256 (repacked)
#define OFF_XG   7259776   // 64*256
#define OFF_F1   7276160   // 64*256
#define OFF_F2   7292544   // 64*256
#define OFF_Y3   7308928   // 64*128
// total 7317120 floats = 29.3 MB

// ---------------- conv layer 1: 3ch 80x80 -> 24ch 40x40, relu ----------------
__global__ __launch_bounds__(256) void k_conv_first(
    const float* __restrict__ img, const float* __restrict__ img2,
    const float* __restrict__ w, const float* __restrict__ bias,
    float* __restrict__ out)
{
    const int idx = blockIdx.x * 256 + threadIdx.x;
    if (idx >= 128*24*40*40) return;
    const int wo = idx % 40;
    const int ho = (idx / 40) % 40;
    const int co = (idx / 1600) % 24;
    const int b  = idx / (1600*24);
    const float* in = (b < 64 ? img : img2) + (size_t)(b & 63) * 3 * 6400;
    float s = bias[co];
    for (int ci = 0; ci < 3; ++ci) {
        const float* ip = in + (size_t)ci * 6400;
        const float* wp = w + (co*3 + ci) * 9;
        #pragma unroll
        for (int kh = 0; kh < 3; ++kh) {
            const int ih = 2*ho - 1 + kh;
            if (ih < 0 || ih >= 80) continue;
            #pragma unroll
            for (int kw = 0; kw < 3; ++kw) {
                const int iw = 2*wo - 1 + kw;
                if (iw < 0 || iw >= 80) continue;
                s += ip[ih*80 + iw] * wp[kh*3 + kw];
            }
        }
    }
    out[idx] = fmaxf(s, 0.f);
}

// ---------------- generic conv layers 2-4: 24ch, BN of input fused ----------------
__global__ __launch_bounds__(256) void k_conv(
    const float* __restrict__ in, const float* __restrict__ ss,
    const float* __restrict__ w, const float* __restrict__ bias,
    float* __restrict__ out, int IH, int IW, int OH, int OW)
{
    const int idx = blockIdx.x * 256 + threadIdx.x;
    const int total = 128*24*OH*OW;
    if (idx >= total) return;
    const int wo = idx % OW;
    const int ho = (idx / OW) % OH;
    const int co = (idx / (OW*OH)) % 24;
    const int b  = idx / (OW*OH*24);
    const float* sc = ss + (b >> 6) * 48;   // [0..23]=scale, [24..47]=shift (per image)
    float s = bias[co];
    for (int ci = 0; ci < 24; ++ci) {
        const float scale = sc[ci], shift = sc[24 + ci];
        const float* ip = in + (size_t)(b*24 + ci) * IH * IW;
        const float* wp = w + (co*24 + ci) * 9;
        #pragma unroll
        for (int kh = 0; kh < 3; ++kh) {
            const int ih = 2*ho - 1 + kh;
            if (ih < 0 || ih >= IH) continue;
            #pragma unroll
            for (int kw = 0; kw < 3; ++kw) {
                const int iw = 2*wo - 1 + kw;
                if (iw < 0 || iw >= IW) continue;
                s += (ip[ih*IW + iw] * scale + shift) * wp[kh*3 + kw];
            }
        }
    }
    out[idx] = fmaxf(s, 0.f);
}

// ---------------- BN batch stats -> scale/shift, per (image, channel) ----------------
__global__ __launch_bounds__(256) void k_stats(
    const float* __restrict__ y, const float* __restrict__ g, const float* __restrict__ beta,
    float* __restrict__ ss, int HW)
{
    const int img = blockIdx.x / 24, c = blockIdx.x % 24;
    const int N = 64 * HW;
    float sum = 0.f, sq = 0.f;
    for (int i = threadIdx.x; i < N; i += 256) {
        const int bb = i / HW, j = i - bb*HW;
        const float v = y[(size_t)((img*64 + bb)*24 + c) * HW + j];
        sum += v; sq += v*v;
    }
    #pragma unroll
    for (int off = 32; off > 0; off >>= 1) {
        sum += __shfl_down(sum, off);
        sq  += __shfl_down(sq, off);
    }
    __shared__ float red[8];
    const int lane = threadIdx.x & 63, wid = threadIdx.x >> 6;
    if (lane == 0) { red[wid] = sum; red[4 + wid] = sq; }
    __syncthreads();
    if (threadIdx.x == 0) {
        const float S  = red[0] + red[1] + red[2] + red[3];
        const float Q2 = red[4] + red[5] + red[6] + red[7];
        const float mean = S / (float)N;
        const float var  = Q2 / (float)N - mean*mean;
        const float rstd = rsqrtf(var + EPSF);
        const float scale = g[c] * rstd;
        ss[img*48 + c]      = scale;
        ss[img*48 + 24 + c] = beta[c] - mean * scale;
    }
}

// ---------------- feature build: [128][25][26] (BN of conv4 fused) ----------------
__global__ __launch_bounds__(256) void k_feat(
    const float* __restrict__ x, const float* __restrict__ ss, float* __restrict__ feat)
{
    const int idx = blockIdx.x * 256 + threadIdx.x;
    if (idx >= 128*25*26) return;
    const int f = idx % 26;
    const int cell = (idx / 26) % 25;
    const int b = idx / 650;
    float v;
    if (f < 24) {
        const float raw = x[(size_t)(b*24 + f)*25 + cell];
        const float* sc = ss + (b >> 6) * 48;
        v = raw * sc[f] + sc[24 + f];
    } else if (f == 24) {
        v = ((float)cell / 5.0f - 2.0f) * 0.5f;   // true division, per reference
    } else {
        v = ((float)(cell % 5) - 2.0f) * 0.5f;
    }
    feat[idx] = v;
}

// ---------------- U,V: [64*25][256] each (layer-1 low-rank decomposition) ----------------
__global__ __launch_bounds__(256) void k_uv(
    const float* __restrict__ feat, const float* __restrict__ w1,
    float* __restrict__ Ub, float* __restrict__ Vb)
{
    const int idx = blockIdx.x * 256 + threadIdx.x;   // row*256 + o, rows = img1 rows [0,1600)
    const int o = idx & 255, row = idx >> 8;
    if (row >= 1600) return;
    const float* f = feat + row * 26;
    const float* wa = w1 + (size_t)o * 702;
    float su = 0.f, sv = 0.f;
    #pragma unroll
    for (int k = 0; k < 26; ++k) {
        const float fv = f[k];
        su += wa[k] * fv;        // W1[:, 0:26]  pairs with feat[b,c] (inner index)
        sv += wa[26 + k] * fv;   // W1[:, 26:52] pairs with feat[b,a] (outer index)
    }
    Ub[idx] = su;
    Vb[idx] = sv;
}

// ---------------- Q: [64][256] = qst @ W1[:,52:].T + b1 ----------------
__global__ __launch_bounds__(256) void k_q(
    const float* __restrict__ feat, const float* __restrict__ w1,
    const float* __restrict__ gb, float* __restrict__ Qb)
{
    const int idx = blockIdx.x * 256 + threadIdx.x;   // 64*256
    if (idx >= 16384) return;
    const int b = idx & 63, o = idx >> 6;
    const float* f = feat + (size_t)(64 + b) * 650;   // img2 features, flattened = qst
    const float* wr = w1 + (size_t)o * 702 + 52;
    float s = gb[o];                                  // g_b[0]
    for (int k = 0; k < 650; ++k) s += wr[k] * f[k];
    Qb[b*256 + o] = s;
}

// ---------------- repack g_w234 [3][256][256] -> Wt4 [l][k/4][o][4] ----------------
__global__ __launch_bounds__(256) void k_wt(const float* __restrict__ w, float* __restrict__ wt)
{
    const int idx = blockIdx.x * 256 + threadIdx.x;
    if (idx >= 3*65536) return;
    const int l   = idx >> 16;
    const int rem = idx & 65535;
    const int kb  = rem >> 10;
    const int o   = (rem >> 2) & 255;
    const int kk  = rem & 3;
    wt[idx] = w[(size_t)l*65536 + o*256 + kb*4 + kk];
}

__global__ __launch_bounds__(256) void k_zero(float* __restrict__ p, int n)
{
    const int i = blockIdx.x * 256 + threadIdx.x;
    if (i < n) p[i] = 0.f;
}

// ---------------- fused g2/g3/g4 + sum pool ----------------
// block: 256 thr = 4 waves; 64-row tile in LDS; thread (og,rg) computes outputs
// {og, og+64, og+128, og+192} for rows rg*16..rg*16+15, acc in registers.
__global__ __launch_bounds__(256) void k_gmlp(
    const float* __restrict__ U, const float* __restrict__ V, const float* __restrict__ Q,
    const float* __restrict__ Wt4, const float* __restrict__ gb, float* __restrict__ xg)
{
    __shared__ float h[64][256];          // 64 KB
    const int b    = blockIdx.x / 10;
    const int row0 = (blockIdx.x % 10) * 64;
    const int og = threadIdx.x & 63;
    const int rg = threadIdx.x >> 6;

    // layer 1: h = relu(U[b,c] + V[b,a] + Q[b])
    {
        const float q0 = Q[b*256 + og],       q1 = Q[b*256 + og + 64];
        const float q2 = Q[b*256 + og + 128], q3 = Q[b*256 + og + 192];
        #pragma unroll
        for (int rr = 0; rr < 16; ++rr) {
            const int r = rg*16 + rr;
            const int p = row0 + r;
            const bool ok = (p < 625);
            const int pc = ok ? p : 624;
            const float* u = U + (size_t)(b*25 + pc % 25) * 256;  // inner index c
            const float* v = V + (size_t)(b*25 + pc / 25) * 256;  // outer index a
            h[r][og]       = ok ? fmaxf(u[og]       + v[og]       + q0, 0.f) : 0.f;
            h[r][og + 64]  = ok ? fmaxf(u[og + 64]  + v[og + 64]  + q1, 0.f) : 0.f;
            h[r][og + 128] = ok ? fmaxf(u[og + 128] + v[og + 128] + q2, 0.f) : 0.f;
            h[r][og + 192] = ok ? fmaxf(u[og + 192] + v[og + 192] + q3, 0.f) : 0.f;
        }
    }
    __syncthreads();

    float acc[4][16];
    #pragma unroll 1
    for (int l = 0; l < 3; ++l) {
        #pragma unroll
        for (int j = 0; j < 4; ++j)
            #pragma unroll
            for (int rr = 0; rr < 16; ++rr) acc[j][rr] = 0.f;

        const float4* wl4 = (const float4*)Wt4 + (size_t)l * 16384;
        for (int kg = 0; kg < 64; ++kg) {
            const float4* wk = wl4 + kg * 256;
            const float4 w0 = wk[og], w1 = wk[og + 64], w2 = wk[og + 128], w3 = wk[og + 192];
            #pragma unroll
            for (int rr = 0; rr < 16; ++rr) {
                const float4 hv = *(const float4*)&h[rg*16 + rr][kg*4];
                acc[0][rr] += w0.x*hv.x + w0.y*hv.y + w0.z*hv.z + w0.w*hv.w;
                acc[1][rr] += w1.x*hv.x + w1.y*hv.y + w1.z*hv.z + w1.w*hv.w;
                acc[2][rr] += w2.x*hv.x + w2.y*hv.y + w2.z*hv.z + w2.w*hv.w;
                acc[3][rr] += w3.x*hv.x + w3.y*hv.y + w3.z*hv.z + w3.w*hv.w;
            }
        }
        const float b0 = gb[(l+1)*256 + og],       b1 = gb[(l+1)*256 + og + 64];
        const float b2 = gb[(l+1)*256 + og + 128], b3 = gb[(l+1)*256 + og + 192];
        __syncthreads();   // all reads of h done before overwrite
        if (l < 2) {
            #pragma unroll
            for (int rr = 0; rr < 16; ++rr) {
                const int r = rg*16 + rr;
                h[r][og]       = fmaxf(acc[0][rr] + b0, 0.f);
                h[r][og + 64]  = fmaxf(acc[1][rr] + b1, 0.f);
                h[r][og + 128] = fmaxf(acc[2][rr] + b2, 0.f);
                h[r][og + 192] = fmaxf(acc[3][rr] + b3, 0.f);
            }
            __syncthreads();
        } else {
            float s0 = 0.f, s1 = 0.f, s2 = 0.f, s3 = 0.f;
            #pragma unroll
            for (int rr = 0; rr < 16; ++rr) {
                if (row0 + rg*16 + rr < 625) {   // mask padded rows out of the pool
                    s0 += fmaxf(acc[0][rr] + b0, 0.f);
                    s1 += fmaxf(acc[1][rr] + b1, 0.f);
                    s2 += fmaxf(acc[2][rr] + b2, 0.f);
                    s3 += fmaxf(acc[3][rr] + b3, 0.f);
                }
            }
            atomicAdd(&xg[b*256 + og],       s0);
            atomicAdd(&xg[b*256 + og + 64],  s1);
            atomicAdd(&xg[b*256 + og + 128], s2);
            atomicAdd(&xg[b*256 + og + 192], s3);
        }
    }
}

// ---------------- small FC layers ----------------
__global__ __launch_bounds__(256) void k_fc(
    const float* __restrict__ in, const float* __restrict__ w,
    const float* __restrict__ bias, float* __restrict__ out,
    int IN, int OUT, int dorelu)
{
    const int idx = blockIdx.x * 256 + threadIdx.x;
    if (idx >= 64 * OUT) return;
    const int b = idx & 63, o = idx >> 6;   // wave-uniform o -> broadcast weight reads
    const float* wr = w + (size_t)o * IN;
    const float* xr = in + (size_t)b * IN;
    float s = bias[o];
    for (int k = 0; k < IN; ++k) s += wr[k] * xr[k];
    out[b*OUT + o] = dorelu ? fmaxf(s, 0.f) : s;
}

// ---------------- grouped softmax (16 groups of 8) + lower clip ----------------
__global__ __launch_bounds__(256) void k_softmax(const float* __restrict__ y, float* __restrict__ out)
{
    const int idx = blockIdx.x * 256 + threadIdx.x;   // 64*16 groups
    if (idx >= 64*16) return;
    const float* p = y + idx * 8;
    float m = p[0];
    #pragma unroll
    for (int i = 1; i < 8; ++i) m = fmaxf(m, p[i]);
    float e[8], s = 0.f;
    #pragma unroll
    for (int i = 0; i < 8; ++i) { e[i] = expf(p[i] - m); s += e[i]; }
    const float inv = 1.f / s;
    #pragma unroll
    for (int i = 0; i < 8; ++i) out[idx*8 + i] = fmaxf(e[i] * inv, 0.001f);
    // upper clip vs global max is a no-op: y <= max(y) elementwise by definition
}

extern "C" void kernel_launch(void* const* d_in, const int* in_sizes, int n_in,
                              void* d_out, int out_size, void* d_ws, size_t ws_size,
                              hipStream_t stream)
{
    const float* img   = (const float*)d_in[0];
    const float* img2  = (const float*)d_in[1];
    const float* cw1   = (const float*)d_in[2];
    const float* cw234 = (const float*)d_in[3];
    const float* cb    = (const float*)d_in[4];
    const float* bng   = (const float*)d_in[5];
    const float* bnb   = (const float*)d_in[6];
    const float* gw1   = (const float*)d_in[7];
    const float* gw234 = (const float*)d_in[8];
    const float* gb    = (const float*)d_in[9];
    const float* fw1   = (const float*)d_in[10];
    const float* fb1   = (const float*)d_in[11];
    const float* fc2w  = (const float*)d_in[12];
    const float* fc2b  = (const float*)d_in[13];
    const float* fc3w  = (const float*)d_in[14];
    const float* fc3b  = (const float*)d_in[15];

    float* ws = (float*)d_ws;
    float* P0 = ws + OFF_P0;  float* P1 = ws + OFF_P1;  float* SS = ws + OFF_SS;
    float* FE = ws + OFF_FEAT; float* Ub = ws + OFF_U;  float* Vb = ws + OFF_V;
    float* Qb = ws + OFF_Q;   float* WT = ws + OFF_WT;  float* XG = ws + OFF_XG;
    float* F1 = ws + OFF_F1;  float* F2 = ws + OFF_F2;  float* Y3 = ws + OFF_Y3;
    float* out = (float*)d_out;

    // CNN: both images as one 128-batch; per-image BN stats; BN fused into consumer loads
    hipLaunchKernelGGL(k_conv_first, dim3(19200), dim3(256), 0, stream, img, img2, cw1, cb, P0);
    hipLaunchKernelGGL(k_stats, dim3(48), dim3(256), 0, stream, P0, bng,    bnb,    SS,      1600);
    hipLaunchKernelGGL(k_conv,  dim3(4800), dim3(256), 0, stream, P0, SS,      cw234,        cb+24, P1, 40,40,20,20);
    hipLaunchKernelGGL(k_stats, dim3(48), dim3(256), 0, stream, P1, bng+24, bnb+24, SS+96,   400);
    hipLaunchKernelGGL(k_conv,  dim3(1200), dim3(256), 0, stream, P1, SS+96,   cw234+5184,   cb+48, P0, 20,20,10,10);
    hipLaunchKernelGGL(k_stats, dim3(48), dim3(256), 0, stream, P0, bng+48, bnb+48, SS+192,  100);
    hipLaunchKernelGGL(k_conv,  dim3(300),  dim3(256), 0, stream, P0, SS+192,  cw234+10368,  cb+72, P1, 10,10,5,5);
    hipLaunchKernelGGL(k_stats, dim3(48), dim3(256), 0, stream, P1, bng+72, bnb+72, SS+288,  25);

    // features + layer-1 low-rank pieces
    hipLaunchKernelGGL(k_feat, dim3(325),  dim3(256), 0, stream, P1, SS+288, FE);
    hipLaunchKernelGGL(k_uv,   dim3(1600), dim3(256), 0, stream, FE, gw1, Ub, Vb);
    hipLaunchKernelGGL(k_q,    dim3(64),   dim3(256), 0, stream, FE, gw1, gb, Qb);
    hipLaunchKernelGGL(k_wt,   dim3(768),  dim3(256), 0, stream, gw234, WT);
    hipLaunchKernelGGL(k_zero, dim3(64),   dim3(256), 0, stream, XG, 16384);

    // fused g-MLP (layers 2-4) + sum pooling
    hipLaunchKernelGGL(k_gmlp, dim3(640), dim3(256), 0, stream, Ub, Vb, Qb, WT, gb, XG);

    // f-MLP + grouped softmax
    hipLaunchKernelGGL(k_fc, dim3(64), dim3(256), 0, stream, XG, fw1,  fb1,  F1, 256, 256, 1);
    hipLaunchKernelGGL(k_fc, dim3(64), dim3(256), 0, stream, F1, fc2w, fc2b, F2, 256, 256, 1);
    hipLaunchKernelGGL(k_fc, dim3(32), dim3(256), 0, stream, F2, fc3w, fc3b, Y3, 256, 128, 0);
    hipLaunchKernelGGL(k_softmax, dim3(4), dim3(256), 0, stream, Y3, out);
}

// Round 4
// 1011.807 us; speedup vs baseline: 1.0396x; 1.0396x over previous
//
#include <hip/hip_runtime.h>

typedef short bf16x8 __attribute__((ext_vector_type(8)));
typedef float f32x4  __attribute__((ext_vector_type(4)));

#define EPSF 1e-5f

// ---------------- workspace layout (float element offsets) ----------------
#define OFF_P0   0          // 4,915,200 floats (conv ping)
#define OFF_U    1048576    //   409,600 (in P0 tail; conv3 out is only 307,200 -> no overlap)
#define OFF_V    1572864    //   409,600
#define OFF_P1   4915200    // 1,228,800 (conv pong)
#define OFF_SS   6144000    // 384
#define OFF_SACC 6144384    // 96 (+pad)
#define OFF_Q    6144512    // 16,384
#define OFF_WP   6160896    // 196,608 float-slots: WP_hi (98,304) + WP_lo (98,304)
#define OFF_W1UV 6357504    // 13,312  (52 x 256)
#define OFF_W1Q  6370816    // 166,400 (650 x 256)
#define OFF_FW1T 6537216    // 65,536
#define OFF_FC2T 6602752    // 65,536
#define OFF_FC3T 6668288    // 32,768
#define OFF_XG   6701056    // 16,384
// end: 6,717,440 floats = 25.6 MiB (round-0 used 29.3 MB successfully)

__device__ __forceinline__ unsigned short f2bf(float f) {
    union { float f; unsigned u; } cv; cv.f = f;
    const unsigned u = cv.u;
    return (unsigned short)((u + 0x7fffu + ((u >> 16) & 1u)) >> 16);  // RNE
}
__device__ __forceinline__ float bf2f(unsigned short h) {
    union { unsigned u; float f; } cv; cv.u = (unsigned)h << 16; return cv.f;
}

// ---------------- prep: zero + weight repacks (hi/lo split) ----------------
__global__ __launch_bounds__(256) void k_prep(
    const float* __restrict__ gw1, const float* __restrict__ gw234,
    const float* __restrict__ fw1, const float* __restrict__ fc2w,
    const float* __restrict__ fc3w, float* __restrict__ ws)
{
    int idx = blockIdx.x * 256 + threadIdx.x;
    if (idx < 16384) { ws[OFF_XG + idx] = 0.f; return; }
    idx -= 16384;
    if (idx < 96) { ws[OFF_SACC + idx] = 0.f; return; }
    idx -= 96;
    if (idx < 49152) {
        // frag f: WP[f][8] ; f = ((l*8+kb)*16+nt)*64+lane ; lo copy at frag offset 24576
        const int isLo = idx >= 24576;
        const int f = isLo ? idx - 24576 : idx;
        const int lane = f & 63;
        const int nt = (f >> 6) & 15;
        const int kb = (f >> 10) & 7;
        const int l  = f >> 13;
        const int o = nt * 16 + (lane & 15);
        const int k = kb * 32 + (lane >> 4) * 8;
        const float* src = gw234 + ((size_t)l * 256 + o) * 256 + k;
        unsigned short* dst = (unsigned short*)(ws + OFF_WP) + (size_t)idx * 8;
        #pragma unroll
        for (int j = 0; j < 8; ++j) {
            const float x = src[j];
            const unsigned short hi = f2bf(x);
            dst[j] = isLo ? f2bf(x - bf2f(hi)) : hi;
        }
        return;
    }
    idx -= 49152;
    if (idx < 13312) {  // W1uvT[k*256+o] = gw1[o*702+k], k<52
        const int o = idx & 255, k = idx >> 8;
        ws[OFF_W1UV + idx] = gw1[(size_t)o * 702 + k];
        return;
    }
    idx -= 13312;
    if (idx < 166400) { // W1qT[k*256+o] = gw1[o*702+52+k], k<650
        const int o = idx & 255, k = idx >> 8;
        ws[OFF_W1Q + idx] = gw1[(size_t)o * 702 + 52 + k];
        return;
    }
    idx -= 166400;
    if (idx < 65536) { const int o = idx & 255, k = idx >> 8; ws[OFF_FW1T + idx] = fw1[o * 256 + k];  return; }
    idx -= 65536;
    if (idx < 65536) { const int o = idx & 255, k = idx >> 8; ws[OFF_FC2T + idx] = fc2w[o * 256 + k]; return; }
    idx -= 65536;
    if (idx < 32768) { const int o = idx & 127, k = idx >> 7; ws[OFF_FC3T + idx] = fc3w[o * 256 + k]; return; }
}

// ---------------- conv layer 1: 3ch 80x80 -> 24ch 40x40, relu ----------------
__global__ __launch_bounds__(256) void k_conv_first(
    const float* __restrict__ img, const float* __restrict__ img2,
    const float* __restrict__ w, const float* __restrict__ bias,
    float* __restrict__ out)
{
    const int idx = blockIdx.x * 256 + threadIdx.x;
    if (idx >= 128*24*40*40) return;
    const int wo = idx % 40;
    const int ho = (idx / 40) % 40;
    const int co = (idx / 1600) % 24;
    const int b  = idx / (1600*24);
    const float* in = (b < 64 ? img : img2) + (size_t)(b & 63) * 3 * 6400;
    float s = bias[co];
    for (int ci = 0; ci < 3; ++ci) {
        const float* ip = in + (size_t)ci * 6400;
        const float* wp = w + (co*3 + ci) * 9;
        #pragma unroll
        for (int kh = 0; kh < 3; ++kh) {
            const int ih = 2*ho - 1 + kh;
            if (ih < 0 || ih >= 80) continue;
            #pragma unroll
            for (int kw = 0; kw < 3; ++kw) {
                const int iw = 2*wo - 1 + kw;
                if (iw < 0 || iw >= 80) continue;
                s += ip[ih*80 + iw] * wp[kh*3 + kw];
            }
        }
    }
    out[idx] = fmaxf(s, 0.f);
}

// ---------------- generic conv layers 2-4: 24ch, BN of input fused ----------------
__global__ __launch_bounds__(256) void k_conv(
    const float* __restrict__ in, const float* __restrict__ ss,
    const float* __restrict__ w, const float* __restrict__ bias,
    float* __restrict__ out, int IH, int IW, int OH, int OW)
{
    const int idx = blockIdx.x * 256 + threadIdx.x;
    const int total = 128*24*OH*OW;
    if (idx >= total) return;
    const int wo = idx % OW;
    const int ho = (idx / OW) % OH;
    const int co = (idx / (OW*OH)) % 24;
    const int b  = idx / (OW*OH*24);
    const float* sc = ss + (b >> 6) * 48;
    float s = bias[co];
    for (int ci = 0; ci < 24; ++ci) {
        const float scale = sc[ci], shift = sc[24 + ci];
        const float* ip = in + (size_t)(b*24 + ci) * IH * IW;
        const float* wp = w + (co*24 + ci) * 9;
        #pragma unroll
        for (int kh = 0; kh < 3; ++kh) {
            const int ih = 2*ho - 1 + kh;
            if (ih < 0 || ih >= IH) continue;
            #pragma unroll
            for (int kw = 0; kw < 3; ++kw) {
                const int iw = 2*wo - 1 + kw;
                if (iw < 0 || iw >= IW) continue;
                s += (ip[ih*IW + iw] * scale + shift) * wp[kh*3 + kw];
            }
        }
    }
    out[idx] = fmaxf(s, 0.f);
}

// ---------------- split-k BN stats (layer 1) ----------------
__global__ __launch_bounds__(256) void k_stats_part(
    const float* __restrict__ y, float* __restrict__ sacc, int HW)
{
    const int img = blockIdx.x / (24*8);
    const int c   = (blockIdx.x / 8) % 24;
    const int sp  = blockIdx.x % 8;
    const int N = 64 * HW, chunk = N / 8;
    float sum = 0.f, sq = 0.f;
    for (int i = sp*chunk + threadIdx.x; i < (sp+1)*chunk; i += 256) {
        const int bb = i / HW, j = i - bb*HW;
        const float v = y[(size_t)((img*64 + bb)*24 + c) * HW + j];
        sum += v; sq += v*v;
    }
    #pragma unroll
    for (int off = 32; off > 0; off >>= 1) {
        sum += __shfl_down(sum, off);
        sq  += __shfl_down(sq, off);
    }
    __shared__ float red[8];
    const int lane = threadIdx.x & 63, wid = threadIdx.x >> 6;
    if (lane == 0) { red[wid] = sum; red[4 + wid] = sq; }
    __syncthreads();
    if (threadIdx.x == 0) {
        atomicAdd(&sacc[img*24 + c],      red[0]+red[1]+red[2]+red[3]);
        atomicAdd(&sacc[48 + img*24 + c], red[4]+red[5]+red[6]+red[7]);
    }
}

__global__ void k_stats_fin(const float* __restrict__ sacc, const float* __restrict__ g,
                            const float* __restrict__ beta, float* __restrict__ ss, int HW)
{
    const int t = threadIdx.x;
    if (t >= 48) return;
    const int img = t / 24, c = t % 24;
    const float N = 64.f * (float)HW;
    const float mean = sacc[t] / N;
    const float var  = sacc[48 + t] / N - mean*mean;
    const float scale = g[c] * rsqrtf(var + EPSF);
    ss[img*48 + c]      = scale;
    ss[img*48 + 24 + c] = beta[c] - mean * scale;
}

// ---------------- single-pass BN stats (layers 2-4) ----------------
__global__ __launch_bounds__(256) void k_stats(
    const float* __restrict__ y, const float* __restrict__ g, const float* __restrict__ beta,
    float* __restrict__ ss, int HW)
{
    const int img = blockIdx.x / 24, c = blockIdx.x % 24;
    const int N = 64 * HW;
    float sum = 0.f, sq = 0.f;
    for (int i = threadIdx.x; i < N; i += 256) {
        const int bb = i / HW, j = i - bb*HW;
        const float v = y[(size_t)((img*64 + bb)*24 + c) * HW + j];
        sum += v; sq += v*v;
    }
    #pragma unroll
    for (int off = 32; off > 0; off >>= 1) {
        sum += __shfl_down(sum, off);
        sq  += __shfl_down(sq, off);
    }
    __shared__ float red[8];
    const int lane = threadIdx.x & 63, wid = threadIdx.x >> 6;
    if (lane == 0) { red[wid] = sum; red[4 + wid] = sq; }
    __syncthreads();
    if (threadIdx.x == 0) {
        const float S  = red[0]+red[1]+red[2]+red[3];
        const float Q2 = red[4]+red[5]+red[6]+red[7];
        const float mean = S / (float)N;
        const float var  = Q2 / (float)N - mean*mean;
        const float scale = g[c] * rsqrtf(var + EPSF);
        ss[img*48 + c]      = scale;
        ss[img*48 + 24 + c] = beta[c] - mean * scale;
    }
}

// ---------------- U,V (feat inline; coalesced via W1uvT) ----------------
__global__ __launch_bounds__(256) void k_uv(
    const float* __restrict__ P1, const float* __restrict__ SS4,
    const float* __restrict__ w1uvT, float* __restrict__ Ub, float* __restrict__ Vb)
{
    __shared__ float f[26];
    const int row = blockIdx.x;           // b*25+cell, b<64 (img1)
    const int b = row / 25, cell = row % 25;
    const int t = threadIdx.x;
    if (t < 26) {
        float v;
        if (t < 24)      v = P1[((size_t)(b*24 + t))*25 + cell] * SS4[t] + SS4[24 + t];
        else if (t == 24) v = ((float)cell / 5.f - 2.f) * 0.5f;
        else              v = ((float)(cell % 5) - 2.f) * 0.5f;
        f[t] = v;
    }
    __syncthreads();
    float su = 0.f, sv = 0.f;
    #pragma unroll
    for (int k = 0; k < 26; ++k) {
        su += f[k] * w1uvT[k*256 + t];
        sv += f[k] * w1uvT[(26 + k)*256 + t];
    }
    Ub[(size_t)row*256 + t] = su;
    Vb[(size_t)row*256 + t] = sv;
}

// ---------------- Q = qst @ W1q.T + g_b[0] ----------------
__global__ __launch_bounds__(256) void k_q(
    const float* __restrict__ P1, const float* __restrict__ SS4,
    const float* __restrict__ w1qT, const float* __restrict__ gb, float* __restrict__ Qb)
{
    __shared__ float f[650];
    const int b = blockIdx.x, t = threadIdx.x;
    for (int i = t; i < 650; i += 256) {
        const int cell = i / 26, ff = i % 26;
        float v;
        if (ff < 24)      v = P1[((size_t)((64 + b)*24 + ff))*25 + cell] * SS4[48 + ff] + SS4[72 + ff];
        else if (ff == 24) v = ((float)cell / 5.f - 2.f) * 0.5f;
        else               v = ((float)(cell % 5) - 2.f) * 0.5f;
        f[i] = v;
    }
    __syncthreads();
    float s = gb[t];
    #pragma unroll 2
    for (int k = 0; k < 650; ++k) s += f[k] * w1qT[k*256 + t];
    Qb[b*256 + t] = s;
}

// ---------------- MFMA g-MLP (bf16x3 split = fp32 quality) + sum pool ----------------
// block = 128 thr (2 waves), tile = 32 rows x 256 cols; wave w owns rows [w*16,w*16+16).
// h kept as hi+lo bf16 pair in LDS (16 KB + 16 KB), XOR-swizzled byte ^= (row&7)<<4.
// Per tile: acc += Ahi*Bhi + Ahi*Blo + Alo*Bhi  (drops ~2^-18 lo*lo term).
__global__ __launch_bounds__(128) void k_gmlp(
    const float* __restrict__ U, const float* __restrict__ V, const float* __restrict__ Q,
    const unsigned short* __restrict__ WP, const float* __restrict__ gb, float* __restrict__ xg)
{
    __shared__ unsigned short hhi[8192];   // 32x256 bf16
    __shared__ unsigned short hlo[8192];
    const int b    = blockIdx.x / 20;
    const int row0 = (blockIdx.x % 20) * 32;
    const int tid  = threadIdx.x;
    const int lane = tid & 63, w = tid >> 6;
    const int r0 = w * 16;

    // layer 1: wave fills its own rows; h = split(relu(U[b,c] + V[b,a] + Q[b]))
    {
        const float2* Q2 = (const float2*)(Q + b*256);
        const float2 q0 = Q2[lane], q1 = Q2[64 + lane];
        for (int rr = 0; rr < 16; ++rr) {
            const int row = r0 + rr;
            int p = row0 + row; if (p > 624) p = 624;
            const float2* u2p = (const float2*)(U + ((size_t)(b*25 + p % 25)) * 256);
            const float2* v2p = (const float2*)(V + ((size_t)(b*25 + p / 25)) * 256);
            #pragma unroll
            for (int cc = 0; cc < 2; ++cc) {
                const int cp = cc*64 + lane;
                const float2 u2 = u2p[cp], v2 = v2p[cp];
                const float2 q2 = cc ? q1 : q0;
                const float x0 = fmaxf(u2.x + v2.x + q2.x, 0.f);
                const float x1 = fmaxf(u2.y + v2.y + q2.y, 0.f);
                const unsigned short h0 = f2bf(x0), h1 = f2bf(x1);
                const float l0 = x0 - bf2f(h0), l1 = x1 - bf2f(h1);
                const int byte = (row*512 + cp*4) ^ ((row & 7) << 4);
                *(unsigned*)((char*)hhi + byte) = (unsigned)h0 | ((unsigned)h1 << 16);
                *(unsigned*)((char*)hlo + byte) = (unsigned)f2bf(l0) | ((unsigned)f2bf(l1) << 16);
            }
        }
    }
    __syncthreads();

    f32x4 acc[16];
    #pragma unroll 1
    for (int l = 0; l < 3; ++l) {
        #pragma unroll
        for (int nt = 0; nt < 16; ++nt) acc[nt] = (f32x4)0.f;
        const int ar = r0 + (lane & 15);
        #pragma unroll 1
        for (int kb = 0; kb < 8; ++kb) {
            const int off = (ar*512 + kb*64 + (lane >> 4)*16) ^ ((ar & 7) << 4);
            const bf16x8 ahi = *(const bf16x8*)((char*)hhi + off);
            const bf16x8 alo = *(const bf16x8*)((char*)hlo + off);
            const bf16x8* whi = (const bf16x8*)WP + ((size_t)(l*8 + kb)*16)*64 + lane;
            const bf16x8* wlo = whi + 24576;   // lo copy: +24576 fragments
            #pragma unroll 4
            for (int nt = 0; nt < 16; ++nt) {
                const bf16x8 bh = whi[nt*64];
                const bf16x8 bl = wlo[nt*64];
                acc[nt] = __builtin_amdgcn_mfma_f32_16x16x32_bf16(ahi, bh, acc[nt], 0, 0, 0);
                acc[nt] = __builtin_amdgcn_mfma_f32_16x16x32_bf16(ahi, bl, acc[nt], 0, 0, 0);
                acc[nt] = __builtin_amdgcn_mfma_f32_16x16x32_bf16(alo, bh, acc[nt], 0, 0, 0);
            }
        }
        __syncthreads();
        if (l < 2) {
            #pragma unroll
            for (int nt = 0; nt < 16; ++nt) {
                const int col = nt*16 + (lane & 15);
                const float bias = gb[(l+1)*256 + col];
                #pragma unroll
                for (int r = 0; r < 4; ++r) {
                    const int row = r0 + 4*(lane >> 4) + r;
                    const float v = fmaxf(acc[nt][r] + bias, 0.f);
                    const unsigned short hv = f2bf(v);
                    const float lv = v - bf2f(hv);
                    const int byte = (row*512 + col*2) ^ ((row & 7) << 4);
                    *(unsigned short*)((char*)hhi + byte) = hv;
                    *(unsigned short*)((char*)hlo + byte) = f2bf(lv);
                }
            }
            __syncthreads();
        } else {
            #pragma unroll
            for (int nt = 0; nt < 16; ++nt) {
                const int col = nt*16 + (lane & 15);
                const float bias = gb[3*256 + col];
                float s = 0.f;
                #pragma unroll
                for (int r = 0; r < 4; ++r) {
                    const int row = r0 + 4*(lane >> 4) + r;
                    if (row0 + row < 625) s += fmaxf(acc[nt][r] + bias, 0.f);
                }
                s += __shfl_xor(s, 16);
                s += __shfl_xor(s, 32);
                if (lane < 16) atomicAdd(&xg[b*256 + col], s);
            }
        }
    }
}

// ---------------- fused head: fc1+fc2+fc3+grouped softmax ----------------
__global__ __launch_bounds__(256) void k_head(
    const float* __restrict__ XG, const float* __restrict__ fw1T, const float* __restrict__ fb1,
    const float* __restrict__ fc2T, const float* __restrict__ fc2b,
    const float* __restrict__ fc3T, const float* __restrict__ fc3b, float* __restrict__ out)
{
    __shared__ float xa[256], xb[256], ys[128];
    const int b = blockIdx.x, t = threadIdx.x;
    xa[t] = XG[b*256 + t];
    __syncthreads();
    float s = fb1[t];
    #pragma unroll 4
    for (int k = 0; k < 256; ++k) s += xa[k] * fw1T[k*256 + t];
    xb[t] = fmaxf(s, 0.f);
    __syncthreads();
    s = fc2b[t];
    #pragma unroll 4
    for (int k = 0; k < 256; ++k) s += xb[k] * fc2T[k*256 + t];
    xa[t] = fmaxf(s, 0.f);
    __syncthreads();
    if (t < 128) {
        s = fc3b[t];
        #pragma unroll 4
        for (int k = 0; k < 256; ++k) s += xa[k] * fc3T[k*128 + t];
        ys[t] = s;
    }
    __syncthreads();
    if (t < 16) {
        float m = ys[t*8];
        #pragma unroll
        for (int i = 1; i < 8; ++i) m = fmaxf(m, ys[t*8 + i]);
        float e[8], sum = 0.f;
        #pragma unroll
        for (int i = 0; i < 8; ++i) { e[i] = expf(ys[t*8 + i] - m); sum += e[i]; }
        const float inv = 1.f / sum;
        #pragma unroll
        for (int i = 0; i < 8; ++i) out[b*128 + t*8 + i] = fmaxf(e[i]*inv, 0.001f);
    }
}

extern "C" void kernel_launch(void* const* d_in, const int* in_sizes, int n_in,
                              void* d_out, int out_size, void* d_ws, size_t ws_size,
                              hipStream_t stream)
{
    const float* img   = (const float*)d_in[0];
    const float* img2  = (const float*)d_in[1];
    const float* cw1   = (const float*)d_in[2];
    const float* cw234 = (const float*)d_in[3];
    const float* cb    = (const float*)d_in[4];
    const float* bng   = (const float*)d_in[5];
    const float* bnb   = (const float*)d_in[6];
    const float* gw1   = (const float*)d_in[7];
    const float* gw234 = (const float*)d_in[8];
    const float* gb    = (const float*)d_in[9];
    const float* fw1   = (const float*)d_in[10];
    const float* fb1   = (const float*)d_in[11];
    const float* fc2w  = (const float*)d_in[12];
    const float* fc2b  = (const float*)d_in[13];
    const float* fc3w  = (const float*)d_in[14];
    const float* fc3b  = (const float*)d_in[15];

    float* ws = (float*)d_ws;
    float* P0 = ws + OFF_P0;  float* P1 = ws + OFF_P1;   float* SS  = ws + OFF_SS;
    float* SA = ws + OFF_SACC; float* Ub = ws + OFF_U;   float* Vb  = ws + OFF_V;
    float* Qb = ws + OFF_Q;
    unsigned short* WP = (unsigned short*)(ws + OFF_WP);
    float* W1UV = ws + OFF_W1UV; float* W1Q = ws + OFF_W1Q;
    float* FW1T = ws + OFF_FW1T; float* FC2T = ws + OFF_FC2T; float* FC3T = ws + OFF_FC3T;
    float* XG = ws + OFF_XG;
    float* out = (float*)d_out;

    // k_prep total work = 16384+96+49152+13312+166400+65536+65536+32768 = 409,184
    hipLaunchKernelGGL(k_prep, dim3(1599), dim3(256), 0, stream, gw1, gw234, fw1, fc2w, fc3w, ws);

    hipLaunchKernelGGL(k_conv_first, dim3(19200), dim3(256), 0, stream, img, img2, cw1, cb, P0);
    hipLaunchKernelGGL(k_stats_part, dim3(384), dim3(256), 0, stream, P0, SA, 1600);
    hipLaunchKernelGGL(k_stats_fin,  dim3(1),   dim3(64),  0, stream, SA, bng, bnb, SS, 1600);
    hipLaunchKernelGGL(k_conv,  dim3(4800), dim3(256), 0, stream, P0, SS,      cw234,       cb+24, P1, 40,40,20,20);
    hipLaunchKernelGGL(k_stats, dim3(48),   dim3(256), 0, stream, P1, bng+24, bnb+24, SS+96,  400);
    hipLaunchKernelGGL(k_conv,  dim3(1200), dim3(256), 0, stream, P1, SS+96,   cw234+5184,  cb+48, P0, 20,20,10,10);
    hipLaunchKernelGGL(k_stats, dim3(48),   dim3(256), 0, stream, P0, bng+48, bnb+48, SS+192, 100);
    hipLaunchKernelGGL(k_conv,  dim3(300),  dim3(256), 0, stream, P0, SS+192,  cw234+10368, cb+72, P1, 10,10,5,5);
    hipLaunchKernelGGL(k_stats, dim3(48),   dim3(256), 0, stream, P1, bng+72, bnb+72, SS+288, 25);

    hipLaunchKernelGGL(k_uv, dim3(1600), dim3(256), 0, stream, P1, SS+288, W1UV, Ub, Vb);
    hipLaunchKernelGGL(k_q,  dim3(64),   dim3(256), 0, stream, P1, SS+288, W1Q, gb, Qb);

    hipLaunchKernelGGL(k_gmlp, dim3(1280), dim3(128), 0, stream, Ub, Vb, Qb, WP, gb, XG);

    hipLaunchKernelGGL(k_head, dim3(64), dim3(256), 0, stream,
                       XG, FW1T, fb1, FC2T, fc2b, FC3T, fc3b, out);
}

// Round 5
// 839.334 us; speedup vs baseline: 1.2532x; 1.2055x over previous
//
#include <hip/hip_runtime.h>

typedef short bf16x8 __attribute__((ext_vector_type(8)));
typedef float f32x4  __attribute__((ext_vector_type(4)));

#define EPSF 1e-5f

// ---------------- workspace layout (float element offsets) ----------------
#define OFF_P0   0          // 4,915,200 floats (conv ping)
#define OFF_U    1048576    //   409,600 (in P0 tail; conv3 out is only 307,200 -> no overlap)
#define OFF_V    1572864    //   409,600
#define OFF_P1   4915200    // 1,228,800 (conv pong)
#define OFF_SS   6144000    // 384
#define OFF_SACC 6144384    // 96 (+pad)
#define OFF_Q    6144512    // 16,384
#define OFF_WP   6160896    // 196,608 float-slots: WP_hi (98,304) + WP_lo (98,304)
#define OFF_W1UV 6357504    // 13,312  (52 x 256)
#define OFF_W1Q  6370816    // 166,400 (650 x 256)
#define OFF_FW1T 6537216    // 65,536
#define OFF_FC2T 6602752    // 65,536
#define OFF_FC3T 6668288    // 32,768
#define OFF_XG   6701056    // 16,384
// end: 6,717,440 floats = 25.6 MiB

__device__ __forceinline__ unsigned short f2bf(float f) {
    union { float f; unsigned u; } cv; cv.f = f;
    const unsigned u = cv.u;
    return (unsigned short)((u + 0x7fffu + ((u >> 16) & 1u)) >> 16);  // RNE
}
__device__ __forceinline__ float bf2f(unsigned short h) {
    union { unsigned u; float f; } cv; cv.u = (unsigned)h << 16; return cv.f;
}

// ---------------- prep: zero + weight repacks (hi/lo split) ----------------
__global__ __launch_bounds__(256) void k_prep(
    const float* __restrict__ gw1, const float* __restrict__ gw234,
    const float* __restrict__ fw1, const float* __restrict__ fc2w,
    const float* __restrict__ fc3w, float* __restrict__ ws)
{
    int idx = blockIdx.x * 256 + threadIdx.x;
    if (idx < 16384) { ws[OFF_XG + idx] = 0.f; return; }
    idx -= 16384;
    if (idx < 96) { ws[OFF_SACC + idx] = 0.f; return; }
    idx -= 96;
    if (idx < 49152) {
        // frag f: WP[f][8] ; f = ((l*8+kb)*16+nt)*64+lane ; lo copy at frag offset 24576
        const int isLo = idx >= 24576;
        const int f = isLo ? idx - 24576 : idx;
        const int lane = f & 63;
        const int nt = (f >> 6) & 15;
        const int kb = (f >> 10) & 7;
        const int l  = f >> 13;
        const int o = nt * 16 + (lane & 15);
        const int k = kb * 32 + (lane >> 4) * 8;
        const float* src = gw234 + ((size_t)l * 256 + o) * 256 + k;
        unsigned short* dst = (unsigned short*)(ws + OFF_WP) + (size_t)idx * 8;
        #pragma unroll
        for (int j = 0; j < 8; ++j) {
            const float x = src[j];
            const unsigned short hi = f2bf(x);
            dst[j] = isLo ? f2bf(x - bf2f(hi)) : hi;
        }
        return;
    }
    idx -= 49152;
    if (idx < 13312) {  // W1uvT[k*256+o] = gw1[o*702+k], k<52
        const int o = idx & 255, k = idx >> 8;
        ws[OFF_W1UV + idx] = gw1[(size_t)o * 702 + k];
        return;
    }
    idx -= 13312;
    if (idx < 166400) { // W1qT[k*256+o] = gw1[o*702+52+k], k<650
        const int o = idx & 255, k = idx >> 8;
        ws[OFF_W1Q + idx] = gw1[(size_t)o * 702 + 52 + k];
        return;
    }
    idx -= 166400;
    if (idx < 65536) { const int o = idx & 255, k = idx >> 8; ws[OFF_FW1T + idx] = fw1[o * 256 + k];  return; }
    idx -= 65536;
    if (idx < 65536) { const int o = idx & 255, k = idx >> 8; ws[OFF_FC2T + idx] = fc2w[o * 256 + k]; return; }
    idx -= 65536;
    if (idx < 32768) { const int o = idx & 127, k = idx >> 7; ws[OFF_FC3T + idx] = fc3w[o * 256 + k]; return; }
}

// ---------------- conv layer 1: 3ch 80x80 -> 24ch 40x40, relu ----------------
__global__ __launch_bounds__(256) void k_conv_first(
    const float* __restrict__ img, const float* __restrict__ img2,
    const float* __restrict__ w, const float* __restrict__ bias,
    float* __restrict__ out)
{
    const int idx = blockIdx.x * 256 + threadIdx.x;
    if (idx >= 128*24*40*40) return;
    const int wo = idx % 40;
    const int ho = (idx / 40) % 40;
    const int co = (idx / 1600) % 24;
    const int b  = idx / (1600*24);
    const float* in = (b < 64 ? img : img2) + (size_t)(b & 63) * 3 * 6400;
    float s = bias[co];
    for (int ci = 0; ci < 3; ++ci) {
        const float* ip = in + (size_t)ci * 6400;
        const float* wp = w + (co*3 + ci) * 9;
        #pragma unroll
        for (int kh = 0; kh < 3; ++kh) {
            const int ih = 2*ho - 1 + kh;
            if (ih < 0 || ih >= 80) continue;
            #pragma unroll
            for (int kw = 0; kw < 3; ++kw) {
                const int iw = 2*wo - 1 + kw;
                if (iw < 0 || iw >= 80) continue;
                s += ip[ih*80 + iw] * wp[kh*3 + kw];
            }
        }
    }
    out[idx] = fmaxf(s, 0.f);
}

// ---------------- generic conv layers 2-4: 24ch, BN of input fused ----------------
__global__ __launch_bounds__(256) void k_conv(
    const float* __restrict__ in, const float* __restrict__ ss,
    const float* __restrict__ w, const float* __restrict__ bias,
    float* __restrict__ out, int IH, int IW, int OH, int OW)
{
    const int idx = blockIdx.x * 256 + threadIdx.x;
    const int total = 128*24*OH*OW;
    if (idx >= total) return;
    const int wo = idx % OW;
    const int ho = (idx / OW) % OH;
    const int co = (idx / (OW*OH)) % 24;
    const int b  = idx / (OW*OH*24);
    const float* sc = ss + (b >> 6) * 48;
    float s = bias[co];
    for (int ci = 0; ci < 24; ++ci) {
        const float scale = sc[ci], shift = sc[24 + ci];
        const float* ip = in + (size_t)(b*24 + ci) * IH * IW;
        const float* wp = w + (co*24 + ci) * 9;
        #pragma unroll
        for (int kh = 0; kh < 3; ++kh) {
            const int ih = 2*ho - 1 + kh;
            if (ih < 0 || ih >= IH) continue;
            #pragma unroll
            for (int kw = 0; kw < 3; ++kw) {
                const int iw = 2*wo - 1 + kw;
                if (iw < 0 || iw >= IW) continue;
                s += (ip[ih*IW + iw] * scale + shift) * wp[kh*3 + kw];
            }
        }
    }
    out[idx] = fmaxf(s, 0.f);
}

// ---------------- split-k BN stats (layer 1) ----------------
__global__ __launch_bounds__(256) void k_stats_part(
    const float* __restrict__ y, float* __restrict__ sacc, int HW)
{
    const int img = blockIdx.x / (24*8);
    const int c   = (blockIdx.x / 8) % 24;
    const int sp  = blockIdx.x % 8;
    const int N = 64 * HW, chunk = N / 8;
    float sum = 0.f, sq = 0.f;
    for (int i = sp*chunk + threadIdx.x; i < (sp+1)*chunk; i += 256) {
        const int bb = i / HW, j = i - bb*HW;
        const float v = y[(size_t)((img*64 + bb)*24 + c) * HW + j];
        sum += v; sq += v*v;
    }
    #pragma unroll
    for (int off = 32; off > 0; off >>= 1) {
        sum += __shfl_down(sum, off);
        sq  += __shfl_down(sq, off);
    }
    __shared__ float red[8];
    const int lane = threadIdx.x & 63, wid = threadIdx.x >> 6;
    if (lane == 0) { red[wid] = sum; red[4 + wid] = sq; }
    __syncthreads();
    if (threadIdx.x == 0) {
        atomicAdd(&sacc[img*24 + c],      red[0]+red[1]+red[2]+red[3]);
        atomicAdd(&sacc[48 + img*24 + c], red[4]+red[5]+red[6]+red[7]);
    }
}

__global__ void k_stats_fin(const float* __restrict__ sacc, const float* __restrict__ g,
                            const float* __restrict__ beta, float* __restrict__ ss, int HW)
{
    const int t = threadIdx.x;
    if (t >= 48) return;
    const int img = t / 24, c = t % 24;
    const float N = 64.f * (float)HW;
    const float mean = sacc[t] / N;
    const float var  = sacc[48 + t] / N - mean*mean;
    const float scale = g[c] * rsqrtf(var + EPSF);
    ss[img*48 + c]      = scale;
    ss[img*48 + 24 + c] = beta[c] - mean * scale;
}

// ---------------- single-pass BN stats (layers 2-4) ----------------
__global__ __launch_bounds__(256) void k_stats(
    const float* __restrict__ y, const float* __restrict__ g, const float* __restrict__ beta,
    float* __restrict__ ss, int HW)
{
    const int img = blockIdx.x / 24, c = blockIdx.x % 24;
    const int N = 64 * HW;
    float sum = 0.f, sq = 0.f;
    for (int i = threadIdx.x; i < N; i += 256) {
        const int bb = i / HW, j = i - bb*HW;
        const float v = y[(size_t)((img*64 + bb)*24 + c) * HW + j];
        sum += v; sq += v*v;
    }
    #pragma unroll
    for (int off = 32; off > 0; off >>= 1) {
        sum += __shfl_down(sum, off);
        sq  += __shfl_down(sq, off);
    }
    __shared__ float red[8];
    const int lane = threadIdx.x & 63, wid = threadIdx.x >> 6;
    if (lane == 0) { red[wid] = sum; red[4 + wid] = sq; }
    __syncthreads();
    if (threadIdx.x == 0) {
        const float S  = red[0]+red[1]+red[2]+red[3];
        const float Q2 = red[4]+red[5]+red[6]+red[7];
        const float mean = S / (float)N;
        const float var  = Q2 / (float)N - mean*mean;
        const float scale = g[c] * rsqrtf(var + EPSF);
        ss[img*48 + c]      = scale;
        ss[img*48 + 24 + c] = beta[c] - mean * scale;
    }
}

// ---------------- U,V (feat inline; coalesced via W1uvT) ----------------
__global__ __launch_bounds__(256) void k_uv(
    const float* __restrict__ P1, const float* __restrict__ SS4,
    const float* __restrict__ w1uvT, float* __restrict__ Ub, float* __restrict__ Vb)
{
    __shared__ float f[26];
    const int row = blockIdx.x;           // b*25+cell, b<64 (img1)
    const int b = row / 25, cell = row % 25;
    const int t = threadIdx.x;
    if (t < 26) {
        float v;
        if (t < 24)      v = P1[((size_t)(b*24 + t))*25 + cell] * SS4[t] + SS4[24 + t];
        else if (t == 24) v = ((float)cell / 5.f - 2.f) * 0.5f;
        else              v = ((float)(cell % 5) - 2.f) * 0.5f;
        f[t] = v;
    }
    __syncthreads();
    float su = 0.f, sv = 0.f;
    #pragma unroll
    for (int k = 0; k < 26; ++k) {
        su += f[k] * w1uvT[k*256 + t];
        sv += f[k] * w1uvT[(26 + k)*256 + t];
    }
    Ub[(size_t)row*256 + t] = su;
    Vb[(size_t)row*256 + t] = sv;
}

// ---------------- Q = qst @ W1q.T + g_b[0] ----------------
__global__ __launch_bounds__(256) void k_q(
    const float* __restrict__ P1, const float* __restrict__ SS4,
    const float* __restrict__ w1qT, const float* __restrict__ gb, float* __restrict__ Qb)
{
    __shared__ float f[650];
    const int b = blockIdx.x, t = threadIdx.x;
    for (int i = t; i < 650; i += 256) {
        const int cell = i / 26, ff = i % 26;
        float v;
        if (ff < 24)      v = P1[((size_t)((64 + b)*24 + ff))*25 + cell] * SS4[48 + ff] + SS4[72 + ff];
        else if (ff == 24) v = ((float)cell / 5.f - 2.f) * 0.5f;
        else               v = ((float)(cell % 5) - 2.f) * 0.5f;
        f[i] = v;
    }
    __syncthreads();
    float s = gb[t];
    #pragma unroll 2
    for (int k = 0; k < 650; ++k) s += f[k] * w1qT[k*256 + t];
    Qb[b*256 + t] = s;
}

// ---------------- MFMA g-MLP (bf16x3 split = fp32 quality) + sum pool ----------------
// block = 256 thr (4 waves), tile = 64 rows x 256 cols; wave w owns rows [w*16,w*16+16).
// h as hi+lo bf16 in LDS (32 KB + 32 KB), XOR-swizzled byte ^= (row&7)<<4.
// Per tile: acc += Ahi*Bhi + Ahi*Blo + Alo*Bhi  (drops ~2^-18 lo*lo term).
// NOTE: nt loop MUST be fully unrolled — acc[nt] with runtime nt spills to
// scratch (rule #20); round-4's "#pragma unroll 4" cost 865 MB of HBM writes.
__global__ __launch_bounds__(256) void k_gmlp(
    const float* __restrict__ U, const float* __restrict__ V, const float* __restrict__ Q,
    const unsigned short* __restrict__ WP, const float* __restrict__ gb, float* __restrict__ xg)
{
    __shared__ unsigned short hhi[16384];   // 64x256 bf16 = 32 KB
    __shared__ unsigned short hlo[16384];
    const int b    = blockIdx.x / 10;
    const int row0 = (blockIdx.x % 10) * 64;
    const int tid  = threadIdx.x;
    const int lane = tid & 63, w = tid >> 6;
    const int r0 = w * 16;

    // layer 1: wave fills its own 16 rows; h = split(relu(U[b,c] + V[b,a] + Q[b]))
    {
        const float2* Q2 = (const float2*)(Q + b*256);
        const float2 q0 = Q2[lane], q1 = Q2[64 + lane];
        for (int rr = 0; rr < 16; ++rr) {
            const int row = r0 + rr;
            int p = row0 + row; if (p > 624) p = 624;
            const float2* u2p = (const float2*)(U + ((size_t)(b*25 + p % 25)) * 256);
            const float2* v2p = (const float2*)(V + ((size_t)(b*25 + p / 25)) * 256);
            #pragma unroll
            for (int cc = 0; cc < 2; ++cc) {
                const int cp = cc*64 + lane;
                const float2 u2 = u2p[cp], v2 = v2p[cp];
                const float2 q2 = cc ? q1 : q0;
                const float x0 = fmaxf(u2.x + v2.x + q2.x, 0.f);
                const float x1 = fmaxf(u2.y + v2.y + q2.y, 0.f);
                const unsigned short h0 = f2bf(x0), h1 = f2bf(x1);
                const float l0 = x0 - bf2f(h0), l1 = x1 - bf2f(h1);
                const int byte = (row*512 + cp*4) ^ ((row & 7) << 4);
                *(unsigned*)((char*)hhi + byte) = (unsigned)h0 | ((unsigned)h1 << 16);
                *(unsigned*)((char*)hlo + byte) = (unsigned)f2bf(l0) | ((unsigned)f2bf(l1) << 16);
            }
        }
    }
    __syncthreads();

    f32x4 acc[16];
    #pragma unroll 1
    for (int l = 0; l < 3; ++l) {
        #pragma unroll
        for (int nt = 0; nt < 16; ++nt) acc[nt] = (f32x4)0.f;
        const int ar = r0 + (lane & 15);
        #pragma unroll 1
        for (int kb = 0; kb < 8; ++kb) {
            const int off = (ar*512 + kb*64 + (lane >> 4)*16) ^ ((ar & 7) << 4);
            const bf16x8 ahi = *(const bf16x8*)((char*)hhi + off);
            const bf16x8 alo = *(const bf16x8*)((char*)hlo + off);
            const bf16x8* whi = (const bf16x8*)WP + ((size_t)(l*8 + kb)*16)*64 + lane;
            const bf16x8* wlo = whi + 24576;   // lo copy: +24576 fragments
            #pragma unroll
            for (int nt = 0; nt < 16; ++nt) {
                const bf16x8 bh = whi[nt*64];
                const bf16x8 bl = wlo[nt*64];
                acc[nt] = __builtin_amdgcn_mfma_f32_16x16x32_bf16(ahi, bh, acc[nt], 0, 0, 0);
                acc[nt] = __builtin_amdgcn_mfma_f32_16x16x32_bf16(ahi, bl, acc[nt], 0, 0, 0);
                acc[nt] = __builtin_amdgcn_mfma_f32_16x16x32_bf16(alo, bh, acc[nt], 0, 0, 0);
            }
        }
        __syncthreads();
        if (l < 2) {
            #pragma unroll
            for (int nt = 0; nt < 16; ++nt) {
                const int col = nt*16 + (lane & 15);
                const float bias = gb[(l+1)*256 + col];
                #pragma unroll
                for (int r = 0; r < 4; ++r) {
                    const int row = r0 + 4*(lane >> 4) + r;
                    const float v = fmaxf(acc[nt][r] + bias, 0.f);
                    const unsigned short hv = f2bf(v);
                    const float lv = v - bf2f(hv);
                    const int byte = (row*512 + col*2) ^ ((row & 7) << 4);
                    *(unsigned short*)((char*)hhi + byte) = hv;
                    *(unsigned short*)((char*)hlo + byte) = f2bf(lv);
                }
            }
            __syncthreads();
        } else {
            #pragma unroll
            for (int nt = 0; nt < 16; ++nt) {
                const int col = nt*16 + (lane & 15);
                const float bias = gb[3*256 + col];
                float s = 0.f;
                #pragma unroll
                for (int r = 0; r < 4; ++r) {
                    const int row = r0 + 4*(lane >> 4) + r;
                    if (row0 + row < 625) s += fmaxf(acc[nt][r] + bias, 0.f);
                }
                s += __shfl_xor(s, 16);
                s += __shfl_xor(s, 32);
                if (lane < 16) atomicAdd(&xg[b*256 + col], s);
            }
        }
    }
}

// ---------------- fused head: fc1+fc2+fc3+grouped softmax ----------------
__global__ __launch_bounds__(256) void k_head(
    const float* __restrict__ XG, const float* __restrict__ fw1T, const float* __restrict__ fb1,
    const float* __restrict__ fc2T, const float* __restrict__ fc2b,
    const float* __restrict__ fc3T, const float* __restrict__ fc3b, float* __restrict__ out)
{
    __shared__ float xa[256], xb[256], ys[128];
    const int b = blockIdx.x, t = threadIdx.x;
    xa[t] = XG[b*256 + t];
    __syncthreads();
    float s = fb1[t];
    #pragma unroll 4
    for (int k = 0; k < 256; ++k) s += xa[k] * fw1T[k*256 + t];
    xb[t] = fmaxf(s, 0.f);
    __syncthreads();
    s = fc2b[t];
    #pragma unroll 4
    for (int k = 0; k < 256; ++k) s += xb[k] * fc2T[k*256 + t];
    xa[t] = fmaxf(s, 0.f);
    __syncthreads();
    if (t < 128) {
        s = fc3b[t];
        #pragma unroll 4
        for (int k = 0; k < 256; ++k) s += xa[k] * fc3T[k*128 + t];
        ys[t] = s;
    }
    __syncthreads();
    if (t < 16) {
        float m = ys[t*8];
        #pragma unroll
        for (int i = 1; i < 8; ++i) m = fmaxf(m, ys[t*8 + i]);
        float e[8], sum = 0.f;
        #pragma unroll
        for (int i = 0; i < 8; ++i) { e[i] = expf(ys[t*8 + i] - m); sum += e[i]; }
        const float inv = 1.f / sum;
        #pragma unroll
        for (int i = 0; i < 8; ++i) out[b*128 + t*8 + i] = fmaxf(e[i]*inv, 0.001f);
    }
}

extern "C" void kernel_launch(void* const* d_in, const int* in_sizes, int n_in,
                              void* d_out, int out_size, void* d_ws, size_t ws_size,
                              hipStream_t stream)
{
    const float* img   = (const float*)d_in[0];
    const float* img2  = (const float*)d_in[1];
    const float* cw1   = (const float*)d_in[2];
    const float* cw234 = (const float*)d_in[3];
    const float* cb    = (const float*)d_in[4];
    const float* bng   = (const float*)d_in[5];
    const float* bnb   = (const float*)d_in[6];
    const float* gw1   = (const float*)d_in[7];
    const float* gw234 = (const float*)d_in[8];
    const float* gb    = (const float*)d_in[9];
    const float* fw1   = (const float*)d_in[10];
    const float* fb1   = (const float*)d_in[11];
    const float* fc2w  = (const float*)d_in[12];
    const float* fc2b  = (const float*)d_in[13];
    const float* fc3w  = (const float*)d_in[14];
    const float* fc3b  = (const float*)d_in[15];

    float* ws = (float*)d_ws;
    float* P0 = ws + OFF_P0;  float* P1 = ws + OFF_P1;   float* SS  = ws + OFF_SS;
    float* SA = ws + OFF_SACC; float* Ub = ws + OFF_U;   float* Vb  = ws + OFF_V;
    float* Qb = ws + OFF_Q;
    unsigned short* WP = (unsigned short*)(ws + OFF_WP);
    float* W1UV = ws + OFF_W1UV; float* W1Q = ws + OFF_W1Q;
    float* FW1T = ws + OFF_FW1T; float* FC2T = ws + OFF_FC2T; float* FC3T = ws + OFF_FC3T;
    float* XG = ws + OFF_XG;
    float* out = (float*)d_out;

    hipLaunchKernelGGL(k_prep, dim3(1599), dim3(256), 0, stream, gw1, gw234, fw1, fc2w, fc3w, ws);

    hipLaunchKernelGGL(k_conv_first, dim3(19200), dim3(256), 0, stream, img, img2, cw1, cb, P0);
    hipLaunchKernelGGL(k_stats_part, dim3(384), dim3(256), 0, stream, P0, SA, 1600);
    hipLaunchKernelGGL(k_stats_fin,  dim3(1),   dim3(64),  0, stream, SA, bng, bnb, SS, 1600);
    hipLaunchKernelGGL(k_conv,  dim3(4800), dim3(256), 0, stream, P0, SS,      cw234,       cb+24, P1, 40,40,20,20);
    hipLaunchKernelGGL(k_stats, dim3(48),   dim3(256), 0, stream, P1, bng+24, bnb+24, SS+96,  400);
    hipLaunchKernelGGL(k_conv,  dim3(1200), dim3(256), 0, stream, P1, SS+96,   cw234+5184,  cb+48, P0, 20,20,10,10);
    hipLaunchKernelGGL(k_stats, dim3(48),   dim3(256), 0, stream, P0, bng+48, bnb+48, SS+192, 100);
    hipLaunchKernelGGL(k_conv,  dim3(300),  dim3(256), 0, stream, P0, SS+192,  cw234+10368, cb+72, P1, 10,10,5,5);
    hipLaunchKernelGGL(k_stats, dim3(48),   dim3(256), 0, stream, P1, bng+72, bnb+72, SS+288, 25);

    hipLaunchKernelGGL(k_uv, dim3(1600), dim3(256), 0, stream, P1, SS+288, W1UV, Ub, Vb);
    hipLaunchKernelGGL(k_q,  dim3(64),   dim3(256), 0, stream, P1, SS+288, W1Q, gb, Qb);

    hipLaunchKernelGGL(k_gmlp, dim3(640), dim3(256), 0, stream, Ub, Vb, Qb, WP, gb, XG);

    hipLaunchKernelGGL(k_head, dim3(64), dim3(256), 0, stream,
                       XG, FW1T, fb1, FC2T, fc2b, FC3T, fc3b, out);
}